// Round 13
// baseline (4124.737 us; speedup 1.0000x reference)
//
#include <hip/hip_runtime.h>
#include <hip/hip_bf16.h>
#include <cstddef>

#define NN 100000
#define EE 3200000
#define NBIN 64
static const float EF = 3200000.0f;
#define INVN (1.0f / 100000.0f)

// ---------- helpers ----------

__device__ __forceinline__ float wsum(float v) {
  #pragma unroll
  for (int off = 32; off > 0; off >>= 1) v += __shfl_down(v, off, 64);
  return v;  // lane 0 holds wave total
}

// block-level reduce of 32 sums + 32 sumsq -> global atomics. red = shared float[256].
__device__ __forceinline__ void reduce64(float sum[32], float ssq[32], float* red,
                                         float* __restrict__ gsum, float* __restrict__ gssq) {
  const int wid = threadIdx.x >> 6, lane = threadIdx.x & 63;
  #pragma unroll
  for (int j = 0; j < 32; j++) {
    float a = wsum(sum[j]);
    float b = wsum(ssq[j]);
    if (lane == 0) { red[wid * 64 + j] = a; red[wid * 64 + 32 + j] = b; }
  }
  __syncthreads();
  if (threadIdx.x < 64) {
    float t = red[threadIdx.x] + red[64 + threadIdx.x] + red[128 + threadIdx.x] + red[192 + threadIdx.x];
    if (threadIdx.x < 32) unsafeAtomicAdd(&gsum[threadIdx.x], t);
    else                  unsafeAtomicAdd(&gssq[threadIdx.x - 32], t);
  }
}

__device__ __forceinline__ void loadrow(const float* __restrict__ xp, int s, float in[13]) {
  const float4* xr = reinterpret_cast<const float4*>(xp + (size_t)s * 12);
  float4 r0 = xr[0], r1 = xr[1], r2 = xr[2];
  in[0]=r0.x; in[1]=r0.y; in[2]=r0.z; in[3]=r0.w; in[4]=r1.x; in[5]=r1.y; in[6]=r1.z; in[7]=r1.w;
  in[8]=r2.x; in[9]=r2.y; in[10]=r2.z;
}

// pack one edge's src-side contribution: [deg:1 @bit54 | (ey+8)*2^14 @bit27 | (ex+8)*2^14 @bit0]
__device__ __forceinline__ unsigned long long packsea(float x, float y) {
  unsigned int xq = (unsigned int)(fmaf(x, 16384.f, 131072.f) + 0.5f);
  unsigned int yq = (unsigned int)(fmaf(y, 16384.f, 131072.f) + 0.5f);
  return (1ULL << 54) | ((unsigned long long)yq << 27) | (unsigned long long)xq;
}

// ---------- setup kernels ----------

// w2tf[j][k] = d_j * w1b[k][j] (d_j = sign(g1b_j)); b1bf[j] = d_j*b1b[j];
// w2aT[j][0..42]+bias at 43; wpaT[j][0..10]+bias at 11
__global__ __launch_bounds__(256) void k_wprep(const float* __restrict__ w1b,
    const float* __restrict__ b1b, const float* __restrict__ g1b,
    const float* __restrict__ w2a, const float* __restrict__ b2a,
    const float* __restrict__ wpa, const float* __restrict__ bpa,
    float* __restrict__ w2tf, float* __restrict__ b1bf,
    float* __restrict__ w2aT, float* __restrict__ wpaT) {
  int t = threadIdx.x;
  for (int i = t; i < 1024; i += 256) {
    int j = i >> 5, k = i & 31;
    float d = (g1b[j] >= 0.f) ? 1.f : -1.f;
    w2tf[j * 32 + k] = d * w1b[k * 32 + j];
  }
  for (int i = t; i < 32 * 43; i += 256) { int j = i & 31, k = i >> 5; w2aT[j * 44 + k] = w2a[k * 32 + j]; }
  for (int i = t; i < 32 * 11; i += 256) { int j = i & 31, k = i >> 5; wpaT[j * 12 + k] = wpa[k * 32 + j]; }
  if (t < 32) {
    float d = (g1b[t] >= 0.f) ? 1.f : -1.f;
    b1bf[t] = d * b1b[t];
    w2aT[t * 44 + 43] = b2a[t];
    wpaT[t * 12 + 11] = bpa[t];
  }
}

// one edge pass: cnt atomic (returned value = rank within dst),
// ONE u64 fixed-point atomic for (deg, seaX, seaY) per edge, global ea moments in registers
__global__ __launch_bounds__(256) void k_prep(const int* __restrict__ dst, const int* __restrict__ src,
    const float* __restrict__ ea, int* __restrict__ cnt, int* __restrict__ rank,
    unsigned long long* __restrict__ nsd, float* __restrict__ cmom) {
  float p0 = 0, p1 = 0, p2 = 0, p3 = 0, p4 = 0;
  const int S = gridDim.x * 256;
  for (int g = blockIdx.x * 256 + threadIdx.x; g < EE / 4; g += S) {
    int4 d4 = reinterpret_cast<const int4*>(dst)[g];
    int4 s4 = reinterpret_cast<const int4*>(src)[g];
    float4 e0 = reinterpret_cast<const float4*>(ea)[2 * g];
    float4 e1 = reinterpret_cast<const float4*>(ea)[2 * g + 1];
    int r0 = atomicAdd(&cnt[d4.x], 1);
    int r1 = atomicAdd(&cnt[d4.y], 1);
    int r2 = atomicAdd(&cnt[d4.z], 1);
    int r3 = atomicAdd(&cnt[d4.w], 1);
    reinterpret_cast<int4*>(rank)[g] = make_int4(r0, r1, r2, r3);
    atomicAdd(&nsd[s4.x], packsea(e0.x, e0.y));
    atomicAdd(&nsd[s4.y], packsea(e0.z, e0.w));
    atomicAdd(&nsd[s4.z], packsea(e1.x, e1.y));
    atomicAdd(&nsd[s4.w], packsea(e1.z, e1.w));
    p0 += e0.x * e0.x + e0.z * e0.z + e1.x * e1.x + e1.z * e1.z;
    p1 += e0.x * e0.y + e0.z * e0.w + e1.x * e1.y + e1.z * e1.w;
    p2 += e0.y * e0.y + e0.w * e0.w + e1.y * e1.y + e1.w * e1.w;
    p3 += e0.x + e0.z + e1.x + e1.z;
    p4 += e0.y + e0.w + e1.y + e1.w;
  }
  p0 = wsum(p0); p1 = wsum(p1); p2 = wsum(p2); p3 = wsum(p3); p4 = wsum(p4);
  if ((threadIdx.x & 63) == 0) {
    unsafeAtomicAdd(&cmom[0], p0); unsafeAtomicAdd(&cmom[1], p1); unsafeAtomicAdd(&cmom[2], p2);
    unsafeAtomicAdd(&cmom[3], p3); unsafeAtomicAdd(&cmom[4], p4);
  }
}

__global__ __launch_bounds__(1024) void k_scan(const int* __restrict__ cnt,
                                               int* __restrict__ starts) {
  __shared__ int part[1024];
  const int T = 1024, CH = (NN + T - 1) / T;
  int t = threadIdx.x;
  int lo = t * CH, hi = min(lo + CH, NN);
  int s = 0;
  for (int i = lo; i < hi; i++) s += cnt[i];
  part[t] = s; __syncthreads();
  for (int off = 1; off < T; off <<= 1) {
    int v = (t >= off) ? part[t - off] : 0;
    __syncthreads();
    part[t] += v;
    __syncthreads();
  }
  int run = part[t] - s;  // exclusive prefix
  for (int i = lo; i < hi; i++) { starts[i] = run; run += cnt[i]; }
  if (t == T - 1) starts[NN] = EE;
}

// scatter packed 16B edge records (src, ea.x, ea.y, 0) into CSR order; NO atomics
__global__ __launch_bounds__(256) void k_scatter(const int* __restrict__ dst, const int* __restrict__ src,
    const float* __restrict__ ea, const int* __restrict__ starts, const int* __restrict__ rank,
    int4* __restrict__ edg) {
  const int S = gridDim.x * 256;
  for (int g = blockIdx.x * 256 + threadIdx.x; g < EE / 4; g += S) {
    int4 d4 = reinterpret_cast<const int4*>(dst)[g];
    int4 s4 = reinterpret_cast<const int4*>(src)[g];
    int4 r4 = reinterpret_cast<const int4*>(rank)[g];
    float4 e0 = reinterpret_cast<const float4*>(ea)[2 * g];
    float4 e1 = reinterpret_cast<const float4*>(ea)[2 * g + 1];
    edg[starts[d4.x] + r4.x] = make_int4(s4.x, __float_as_int(e0.x), __float_as_int(e0.y), 0);
    edg[starts[d4.y] + r4.y] = make_int4(s4.y, __float_as_int(e0.z), __float_as_int(e0.w), 0);
    edg[starts[d4.z] + r4.z] = make_int4(s4.z, __float_as_int(e1.x), __float_as_int(e1.y), 0);
    edg[starts[d4.w] + r4.w] = make_int4(s4.w, __float_as_int(e1.z), __float_as_int(e1.w), 0);
  }
}

// padded node rows: xp[n][0..9]=x cols 0..9, [10]=x col10 (current), [11]=0
__global__ __launch_bounds__(256) void k_xp(const float* __restrict__ x, float* __restrict__ xp) {
  int n = blockIdx.x * 256 + threadIdx.x;
  if (n >= NN) return;
  float v[11];
  #pragma unroll
  for (int k = 0; k < 11; k++) v[k] = x[(size_t)n * 11 + k];
  float4* o = reinterpret_cast<float4*>(xp + (size_t)n * 12);
  o[0] = make_float4(v[0], v[1], v[2], v[3]);
  o[1] = make_float4(v[4], v[5], v[6], v[7]);
  o[2] = make_float4(v[8], v[9], v[10], 0.f);
}

// ---------- per-conv: input moments (node pass) ----------
__global__ __launch_bounds__(256) void k_mom(const float* __restrict__ xp,
                                             const unsigned long long* __restrict__ nsd,
                                             float* __restrict__ mom) {
  const int n = blockIdx.x * 256 + threadIdx.x;
  const int lane = threadIdx.x & 63;
  float v[11]; float w = 0.f; float sx = 0.f, sy = 0.f;
  #pragma unroll
  for (int k = 0; k < 11; k++) v[k] = 0.f;
  if (n < NN) {
    unsigned long long pv = nsd[n];
    float dg = (float)(unsigned int)(pv >> 54);
    float sxf = (float)(unsigned int)(pv & 0x7FFFFFFull);
    float syf = (float)(unsigned int)((pv >> 27) & 0x7FFFFFFull);
    w = dg;
    sx = sxf * (1.f / 16384.f) - 8.f * dg;
    sy = syf * (1.f / 16384.f) - 8.f * dg;
    loadrow(xp, n, v);
  }
  int ch = 0;
  #pragma unroll
  for (int a = 0; a < 11; a++) {
    float r = wsum(w * v[a]);
    if (lane == 0) unsafeAtomicAdd(&mom[ch], r);
    ch++;
  }
  #pragma unroll
  for (int a = 0; a < 11; a++) {
    #pragma unroll
    for (int b = a; b < 11; b++) {
      float r = wsum(w * v[a] * v[b]);
      if (lane == 0) unsafeAtomicAdd(&mom[ch], r);
      ch++;
    }
  }
  #pragma unroll
  for (int a = 0; a < 11; a++) {
    float rx = wsum(v[a] * sx);
    if (lane == 0) unsafeAtomicAdd(&mom[ch], rx);
    ch++;
    float ry = wsum(v[a] * sy);
    if (lane == 0) unsafeAtomicAdd(&mom[ch], ry);
    ch++;
  }
}

__device__ __forceinline__ float msym(const float* mom, const float* cmom, int k, int l) {
  int a = min(k, l), b = max(k, l);
  if (b < 11) return mom[11 + a * 11 - a * (a - 1) / 2 + (b - a)];
  if (a < 11) return mom[77 + a * 2 + (b - 11)];
  return cmom[(a - 11) + (b - 11)];
}

// ---------- k_P: fused fin1 (per-block BN fold) + P precompute ----------
// block0 also publishes wexy and zeros SUM3/SSQ3 (stats[64..127]) for this conv's hpre2
__global__ __launch_bounds__(256) void k_P(const float* __restrict__ xp,
    const float* __restrict__ mom, const float* __restrict__ cmom,
    const float* __restrict__ w1a, const float* __restrict__ b1a,
    const float* __restrict__ g1a, const float* __restrict__ be1a,
    float* __restrict__ wexy, float* __restrict__ statsbase, float* __restrict__ P) {
  __shared__ float w1fs[32 * 14];
  const int t = threadIdx.x;
  if (t < 32) {
    const int jj = t;
    float w[13], S[13];
    #pragma unroll
    for (int k = 0; k < 13; k++) w[k] = w1a[k * 32 + jj];
    #pragma unroll
    for (int k = 0; k < 11; k++) S[k] = mom[k];
    S[11] = cmom[3]; S[12] = cmom[4];
    float lin = 0.f;
    #pragma unroll
    for (int k = 0; k < 13; k++) lin = fmaf(w[k], S[k], lin);
    float quad = 0.f;
    #pragma unroll
    for (int k = 0; k < 13; k++)
      #pragma unroll
      for (int l = 0; l < 13; l++) quad = fmaf(w[k] * w[l], msym(mom, cmom, k, l), quad);
    const float invE = 1.f / EF;
    float b = b1a[jj];
    float mean = fmaf(lin, invE, b);
    float ey2 = (quad + 2.f * b * lin) * invE + b * b;
    float var = fmaxf(ey2 - mean * mean, 0.f);
    float A = g1a[jj] * rsqrtf(var + 1e-5f);
    float C = be1a[jj] - mean * A;
    #pragma unroll
    for (int k = 0; k < 11; k++) w1fs[jj * 14 + k] = A * w[k];
    w1fs[jj * 14 + 11] = 0.f; w1fs[jj * 14 + 12] = 0.f;
    w1fs[jj * 14 + 13] = fmaf(A, b, C);
    if (blockIdx.x == 0) { wexy[jj] = A * w[11]; wexy[32 + jj] = A * w[12]; }
  }
  // FIX (R12 bug): zero stats[64..127] = SUM3[0..31], SSQ3[0..31] (was stats[0..63])
  if (blockIdx.x == 0 && t >= 64 && t < 128) statsbase[t] = 0.f;
  __syncthreads();
  const int n = blockIdx.x * 256 + t;
  if (n >= NN) return;
  float xv[11];
  loadrow(xp, n, xv);
  float4* op = reinterpret_cast<float4*>(P + (size_t)n * 32);
  #pragma unroll
  for (int jj = 0; jj < 8; jj++) {
    float o[4];
    #pragma unroll
    for (int u = 0; u < 4; u++) {
      int j = 4 * jj + u;
      const float* wr = w1fs + j * 14;
      float acc = wr[13];
      #pragma unroll
      for (int k = 0; k < 11; k++) acc = fmaf(xv[k], wr[k], acc);
      o[u] = acc;
    }
    op[jj] = make_float4(o[0], o[1], o[2], o[3]);
  }
}

// ---------- fused edge pass: lane = channel, k-half split (fp32-exact, R9-verified engine) ----------
__global__ __launch_bounds__(256, 6) void k_fusedagg(
    const int* __restrict__ starts, const int4* __restrict__ edg,
    const float* __restrict__ P, const float* __restrict__ wexy,
    const float* __restrict__ w2tf, const float* __restrict__ b1bf,
    float* __restrict__ tzb, float* __restrict__ gms, float* __restrict__ gzq) {
  __shared__ float smx[4][2][32];
  __shared__ float redm[4][32], redq[4][32];
  const int tid = threadIdx.x;
  const int wid = tid >> 6, lane = tid & 63;
  const int half = lane >> 5, l = lane & 31;
  const int c0 = l & 15, h = (l >> 4) & 1;
  const int n = blockIdx.x * 8 + wid * 2 + half;   // NN = 12500*8 exactly
  const float wex = wexy[l], wey = wexy[32 + l], bz = b1bf[l];
  const float4* wcA = reinterpret_cast<const float4*>(w2tf + (size_t)c0 * 32 + 16 * h);
  const float4* wcB = reinterpret_cast<const float4*>(w2tf + (size_t)(c0 + 16) * 32 + 16 * h);
  const float4 a0 = wcA[0], a1 = wcA[1], a2 = wcA[2], a3 = wcA[3];
  const float4 b0 = wcB[0], b1 = wcB[1], b2 = wcB[2], b3 = wcB[3];
  float tz = -3.0e38f, zq = 0.f, ms = 0.f;
  int lo = 0, hi = 0;
  if (n < NN) { lo = starts[n]; hi = starts[n + 1]; }
  float* msl = &smx[wid][half][0];
  const float* mrd = msl + 16 * h;
  int sl = lo;
  int4 eA = make_int4(0, 0, 0, 0), eB = make_int4(0, 0, 0, 0);
  float pA = 0.f;
  if (sl < hi) {
    eA = edg[sl];
    pA = P[(size_t)eA.x * 32 + l];
  }
  if (sl + 1 < hi) eB = edg[sl + 1];
  while (sl < hi) {
    int4 eC = eB;
    if (sl + 2 < hi) eC = edg[sl + 2];
    float pN = pA;
    if (sl + 1 < hi) pN = P[(size_t)eB.x * 32 + l];
    const float ex = __int_as_float(eA.y), ey = __int_as_float(eA.z);
    const float m = fmaxf(0.f, fmaf(ex, wex, fmaf(ey, wey, pA)));
    ms += m;
    msl[l] = m;
    __builtin_amdgcn_wave_barrier();
    const float4 m0 = *reinterpret_cast<const float4*>(mrd + 0);
    const float4 m1 = *reinterpret_cast<const float4*>(mrd + 4);
    const float4 m2 = *reinterpret_cast<const float4*>(mrd + 8);
    const float4 m3 = *reinterpret_cast<const float4*>(mrd + 12);
    __builtin_amdgcn_wave_barrier();
    float zA0 = 0.f, zA1 = 0.f, zB0 = 0.f, zB1 = 0.f;
    zA0 = fmaf(m0.x, a0.x, zA0); zA1 = fmaf(m0.y, a0.y, zA1);
    zA0 = fmaf(m0.z, a0.z, zA0); zA1 = fmaf(m0.w, a0.w, zA1);
    zA0 = fmaf(m1.x, a1.x, zA0); zA1 = fmaf(m1.y, a1.y, zA1);
    zA0 = fmaf(m1.z, a1.z, zA0); zA1 = fmaf(m1.w, a1.w, zA1);
    zA0 = fmaf(m2.x, a2.x, zA0); zA1 = fmaf(m2.y, a2.y, zA1);
    zA0 = fmaf(m2.z, a2.z, zA0); zA1 = fmaf(m2.w, a2.w, zA1);
    zA0 = fmaf(m3.x, a3.x, zA0); zA1 = fmaf(m3.y, a3.y, zA1);
    zA0 = fmaf(m3.z, a3.z, zA0); zA1 = fmaf(m3.w, a3.w, zA1);
    zB0 = fmaf(m0.x, b0.x, zB0); zB1 = fmaf(m0.y, b0.y, zB1);
    zB0 = fmaf(m0.z, b0.z, zB0); zB1 = fmaf(m0.w, b0.w, zB1);
    zB0 = fmaf(m1.x, b1.x, zB0); zB1 = fmaf(m1.y, b1.y, zB1);
    zB0 = fmaf(m1.z, b1.z, zB0); zB1 = fmaf(m1.w, b1.w, zB1);
    zB0 = fmaf(m2.x, b2.x, zB0); zB1 = fmaf(m2.y, b2.y, zB1);
    zB0 = fmaf(m2.z, b2.z, zB0); zB1 = fmaf(m2.w, b2.w, zB1);
    zB0 = fmaf(m3.x, b3.x, zB0); zB1 = fmaf(m3.y, b3.y, zB1);
    zB0 = fmaf(m3.z, b3.z, zB0); zB1 = fmaf(m3.w, b3.w, zB1);
    float pAh = zA0 + zA1;
    float pBh = zB0 + zB1;
    pAh += __shfl_xor(pAh, 16, 64);
    pBh += __shfl_xor(pBh, 16, 64);
    const float z = ((l & 16) ? pBh : pAh) + bz;
    tz = fmaxf(tz, z);
    zq = fmaf(z, z, zq);
    eA = eB; eB = eC; pA = pN;
    ++sl;
  }
  if (n < NN) tzb[(size_t)n * 32 + l] = tz;
  float msT = ms + __shfl_xor(ms, 32, 64);
  float zqT = zq + __shfl_xor(zq, 32, 64);
  if (lane < 32) { redm[wid][l] = msT; redq[wid][l] = zqT; }
  __syncthreads();
  if (tid < 32) {
    float a = redm[0][tid] + redm[1][tid] + redm[2][tid] + redm[3][tid];
    float b = redq[0][tid] + redq[1][tid] + redq[2][tid] + redq[3][tid];
    const int bin = blockIdx.x & (NBIN - 1);
    unsafeAtomicAdd(&gms[bin * 32 + tid], a);
    unsafeAtomicAdd(&gzq[bin * 32 + tid], b);
  }
}

// ---------- hpre2: fused fin2 (bins -> A2d/C2 per block) + h compute + stats ----------
__global__ __launch_bounds__(256) void k_hpre2(const float* __restrict__ xp,
    const float* __restrict__ tzb, const int* __restrict__ starts,
    const float* __restrict__ gms, const float* __restrict__ gzq,
    const float* __restrict__ w1b, const float* __restrict__ b1b,
    const float* __restrict__ g1b, const float* __restrict__ be1b,
    const float* __restrict__ w2aT,
    float* __restrict__ hpre, float* __restrict__ gsum, float* __restrict__ gssq) {
  __shared__ float red[256], a2s[32], c2s[32], smm[32], szq[32];
  const int t = threadIdx.x;
  if (t < 32) {
    float msj = 0.f, zqj = 0.f;
    for (int b = 0; b < NBIN; b++) { msj += gms[b * 32 + t]; zqj += gzq[b * 32 + t]; }
    smm[t] = msj; szq[t] = zqj;
  }
  __syncthreads();
  if (t < 32) {
    float zs = EF * b1b[t];
    #pragma unroll
    for (int k = 0; k < 32; k++) zs = fmaf(w1b[k * 32 + t], smm[k], zs);
    const float invE = 1.f / EF;
    float mu = zs * invE;
    float var = fmaxf(szq[t] * invE - mu * mu, 0.f);
    float A = g1b[t] * rsqrtf(var + 1e-5f);
    float C = be1b[t] - mu * A;
    float d = (g1b[t] >= 0.f) ? 1.f : -1.f;
    a2s[t] = A * d; c2s[t] = C;
  }
  __syncthreads();
  const int n = blockIdx.x * 256 + t;
  float hh[32], hv[32];
  #pragma unroll
  for (int j = 0; j < 32; j++) hv[j] = 0.f;
  if (n < NN) {
    float xv[11];
    loadrow(xp, n, xv);
    const int dg = starts[n + 1] - starts[n];
    float av[32];
    if (dg > 0) {
      const float4* tp = reinterpret_cast<const float4*>(tzb + (size_t)n * 32);
      #pragma unroll
      for (int j = 0; j < 8; j++) {
        float4 v = tp[j];
        av[4 * j]     = fmaxf(0.f, fmaf(a2s[4 * j],     v.x, c2s[4 * j]));
        av[4 * j + 1] = fmaxf(0.f, fmaf(a2s[4 * j + 1], v.y, c2s[4 * j + 1]));
        av[4 * j + 2] = fmaxf(0.f, fmaf(a2s[4 * j + 2], v.z, c2s[4 * j + 2]));
        av[4 * j + 3] = fmaxf(0.f, fmaf(a2s[4 * j + 3], v.w, c2s[4 * j + 3]));
      }
    } else {
      #pragma unroll
      for (int j = 0; j < 32; j++) av[j] = 0.f;
    }
    #pragma unroll
    for (int j = 0; j < 32; j++) {
      const float* wr = w2aT + j * 44;
      float acc = wr[43];
      #pragma unroll
      for (int k = 0; k < 11; k++) acc = fmaf(xv[k], wr[k], acc);
      #pragma unroll
      for (int k = 0; k < 32; k++) acc = fmaf(av[k], wr[11 + k], acc);
      hv[j] = acc;
    }
    float4* hp = reinterpret_cast<float4*>(hpre + (size_t)n * 32);
    #pragma unroll
    for (int j = 0; j < 8; j++)
      hp[j] = make_float4(hv[4 * j], hv[4 * j + 1], hv[4 * j + 2], hv[4 * j + 3]);
  }
  #pragma unroll
  for (int j = 0; j < 32; j++) hh[j] = hv[j] * hv[j];
  reduce64(hv, hh, red, gsum, gssq);
}

// ---------- comb: fused fin3 + new col10; block0 zeroes mom & gms/gzq for next conv ----------
__global__ __launch_bounds__(256) void k_comb(const float* __restrict__ hpre,
    const float* __restrict__ SUM3, const float* __restrict__ SSQ3,
    const float* __restrict__ g2a, const float* __restrict__ be2a,
    const float* __restrict__ w2b, const float* __restrict__ b2b, float* __restrict__ xp,
    float* __restrict__ mom, float* __restrict__ gms, float* __restrict__ gzq) {
  __shared__ float a3s[32], c3s[32];
  const int t = threadIdx.x;
  if (t < 32) {
    float mu = SUM3[t] * INVN;
    float var = fmaxf(SSQ3[t] * INVN - mu * mu, 0.f);
    float s = rsqrtf(var + 1e-5f) * g2a[t];
    a3s[t] = s; c3s[t] = be2a[t] - mu * s;
  }
  __syncthreads();
  const int n = blockIdx.x * 256 + t;
  if (n < NN) {
    const float4* hp = reinterpret_cast<const float4*>(hpre + (size_t)n * 32);
    float acc = b2b[0];
    #pragma unroll
    for (int j = 0; j < 8; j++) {
      float4 v = hp[j];
      acc += fmaxf(0.f, fmaf(v.x, a3s[4 * j],     c3s[4 * j]))     * w2b[4 * j];
      acc += fmaxf(0.f, fmaf(v.y, a3s[4 * j + 1], c3s[4 * j + 1])) * w2b[4 * j + 1];
      acc += fmaxf(0.f, fmaf(v.z, a3s[4 * j + 2], c3s[4 * j + 2])) * w2b[4 * j + 2];
      acc += fmaxf(0.f, fmaf(v.w, a3s[4 * j + 3], c3s[4 * j + 3])) * w2b[4 * j + 3];
    }
    xp[(size_t)n * 12 + 10] = fmaxf(acc, 0.f);
  }
  if (blockIdx.x == 0) {
    if (t < 128) mom[t] = 0.f;
    for (int i = t; i < NBIN * 32; i += 256) { gms[i] = 0.f; gzq[i] = 0.f; }
  }
}

// ---------- power MLP ----------

__global__ __launch_bounds__(256) void k_p5(const float* __restrict__ xp, const float* __restrict__ wpaT,
                                            float* __restrict__ ybuf,
                                            float* __restrict__ gsum, float* __restrict__ gssq) {
  __shared__ float red[256];
  const int n = blockIdx.x * 256 + threadIdx.x;
  float y[32], yy[32];
  #pragma unroll
  for (int j = 0; j < 32; j++) y[j] = 0.f;
  if (n < NN) {
    float xv[11];
    loadrow(xp, n, xv);
    #pragma unroll
    for (int j = 0; j < 32; j++) {
      const float* wr = wpaT + j * 12;
      float acc = wr[11];
      #pragma unroll
      for (int k = 0; k < 11; k++) acc = fmaf(xv[k], wr[k], acc);
      y[j] = acc;
    }
    float4* yp = reinterpret_cast<float4*>(ybuf + (size_t)n * 32);
    #pragma unroll
    for (int j = 0; j < 8; j++)
      yp[j] = make_float4(y[4 * j], y[4 * j + 1], y[4 * j + 2], y[4 * j + 3]);
  }
  #pragma unroll
  for (int j = 0; j < 32; j++) yy[j] = y[j] * y[j];
  reduce64(y, yy, red, gsum, gssq);
}

// p6: fused fin4 (SUM4 -> a4/c4 per block) + yq + scalar stats
__global__ __launch_bounds__(256) void k_p6(const float* __restrict__ ybuf,
    const float* __restrict__ SUM4, const float* __restrict__ SSQ4,
    const float* __restrict__ gpa, const float* __restrict__ bepa,
    const float* __restrict__ wpb, const float* __restrict__ bpb,
    float* __restrict__ yq, float* __restrict__ gsum, float* __restrict__ gssq) {
  __shared__ float red[8], a4s[32], c4s[32];
  const int t = threadIdx.x;
  if (t < 32) {
    float mu = SUM4[t] * INVN;
    float var = fmaxf(SSQ4[t] * INVN - mu * mu, 0.f);
    float s = rsqrtf(var + 1e-5f) * gpa[t];
    a4s[t] = s; c4s[t] = bepa[t] - mu * s;
  }
  __syncthreads();
  const int n = blockIdx.x * 256 + t;
  float sum = 0.f, ssq = 0.f;
  if (n < NN) {
    const float4* yp = reinterpret_cast<const float4*>(ybuf + (size_t)n * 32);
    float q = bpb[0];
    #pragma unroll
    for (int j = 0; j < 8; j++) {
      float4 v = yp[j];
      q = fmaf(fmaxf(0.f, fmaf(v.x, a4s[4 * j],     c4s[4 * j])),     wpb[4 * j],     q);
      q = fmaf(fmaxf(0.f, fmaf(v.y, a4s[4 * j + 1], c4s[4 * j + 1])), wpb[4 * j + 1], q);
      q = fmaf(fmaxf(0.f, fmaf(v.z, a4s[4 * j + 2], c4s[4 * j + 2])), wpb[4 * j + 2], q);
      q = fmaf(fmaxf(0.f, fmaf(v.w, a4s[4 * j + 3], c4s[4 * j + 3])), wpb[4 * j + 3], q);
    }
    yq[n] = q;
    sum = q; ssq = q * q;
  }
  float s = wsum(sum), qq = wsum(ssq);
  const int wid = t >> 6, lane = t & 63;
  if (lane == 0) { red[wid] = s; red[4 + wid] = qq; }
  __syncthreads();
  if (t == 0) {
    unsafeAtomicAdd(&gsum[0], red[0] + red[1] + red[2] + red[3]);
    unsafeAtomicAdd(&gssq[0], red[4] + red[5] + red[6] + red[7]);
  }
}

// p7: fused fin5
__global__ __launch_bounds__(256) void k_p7(const float* __restrict__ yq,
    const float* __restrict__ SUM5, const float* __restrict__ SSQ5,
    const float* __restrict__ gpb, const float* __restrict__ bepb, float* __restrict__ out) {
  const int n = blockIdx.x * 256 + threadIdx.x;
  if (n >= NN) return;
  float mu = SUM5[0] * INVN;
  float var = fmaxf(SSQ5[0] * INVN - mu * mu, 0.f);
  float a5 = rsqrtf(var + 1e-5f) * gpb[0];
  float c5 = bepb[0] - mu * a5;
  out[n] = fmaxf(0.f, fmaf(yq[n], a5, c5));
}

// ---------- host launch ----------

extern "C" void kernel_launch(void* const* d_in, const int* in_sizes, int n_in,
                              void* d_out, int out_size, void* d_ws, size_t ws_size,
                              hipStream_t stream) {
  const float* x    = (const float*)d_in[0];
  const float* ea   = (const float*)d_in[1];
  const int*   ei   = (const int*)d_in[2];
  const int*   srcp = ei;
  const int*   dstp = ei + EE;
  const float* w1a = (const float*)d_in[3],  *b1a = (const float*)d_in[4];
  const float* g1a = (const float*)d_in[5],  *be1a = (const float*)d_in[6];
  const float* w1b = (const float*)d_in[7],  *b1b = (const float*)d_in[8];
  const float* g1b = (const float*)d_in[9],  *be1b = (const float*)d_in[10];
  const float* w2a = (const float*)d_in[11], *b2a = (const float*)d_in[12];
  const float* g2a = (const float*)d_in[13], *be2a = (const float*)d_in[14];
  const float* w2b = (const float*)d_in[15], *b2b = (const float*)d_in[16];
  const float* wpa = (const float*)d_in[17], *bpa = (const float*)d_in[18];
  const float* gpa = (const float*)d_in[19], *bepa = (const float*)d_in[20];
  const float* wpb = (const float*)d_in[21], *bpb = (const float*)d_in[22];
  const float* gpb = (const float*)d_in[23], *bepb = (const float*)d_in[24];

  size_t off = 0;
  char* base = (char*)d_ws;
  auto alloc = [&](size_t bytes) -> void* {
    void* p = base + off;
    off += (bytes + 255) & ~(size_t)255;
    return p;
  };
  float* stats = (float*)alloc(2048);
  float* mom   = (float*)alloc(512);
  float* cmom  = (float*)alloc(256);
  float* gmsB  = (float*)alloc(NBIN * 32 * 4);
  float* gzqB  = (float*)alloc(NBIN * 32 * 4);
  float* wexy  = (float*)alloc(64 * 4);
  float* w2tf  = (float*)alloc(32 * 32 * 4);
  float* b1bf  = (float*)alloc(256);
  float* w2aT  = (float*)alloc(32 * 44 * 4);
  float* wpaT  = (float*)alloc(32 * 12 * 4);
  int*   cnt    = (int*)alloc(NN * 4);
  unsigned long long* nsd = (unsigned long long*)alloc((size_t)NN * 8);
  int*   starts = (int*)alloc((NN + 1) * 4);
  int*   rank   = (int*)alloc((size_t)EE * 4);
  int4*  edg    = (int4*)alloc((size_t)EE * 16);
  float* xp     = (float*)alloc((size_t)NN * 12 * 4);
  float* P      = (float*)alloc((size_t)NN * 32 * 4);
  float* tzb    = (float*)alloc((size_t)NN * 32 * 4);
  float* hpre   = (float*)alloc((size_t)NN * 32 * 4);
  float* yq     = (float*)alloc(NN * 4);

  float *SUM3 = stats + 64,  *SSQ3 = stats + 96;
  float *SUM4 = stats + 128, *SSQ4 = stats + 160;
  float *SUM5 = stats + 192, *SSQ5 = stats + 224;

  hipMemsetAsync(stats, 0, 2048, stream);
  hipMemsetAsync(mom, 0, 512 + 256, stream);               // mom + cmom (contiguous)
  hipMemsetAsync(gmsB, 0, NBIN * 32 * 4 * 2, stream);      // gmsB + gzqB (contiguous)
  hipMemsetAsync(cnt, 0, NN * 4, stream);
  hipMemsetAsync(nsd, 0, (size_t)NN * 8, stream);

  const int GN = (NN + 255) / 256;          // 391
  const int GW = NN / 8;                    // 12500 blocks: 8 nodes x (4 waves x 2 halves)
  const int GE4 = (EE / 4 + 255) / 256;     // 3125

  k_wprep  <<<1, 256, 0, stream>>>(w1b, b1b, g1b, w2a, b2a, wpa, bpa, w2tf, b1bf, w2aT, wpaT);
  k_prep   <<<GE4, 256, 0, stream>>>(dstp, srcp, ea, cnt, rank, nsd, cmom);
  k_scan   <<<1, 1024, 0, stream>>>(cnt, starts);
  k_scatter<<<GE4, 256, 0, stream>>>(dstp, srcp, ea, starts, rank, edg);
  k_xp     <<<GN, 256, 0, stream>>>(x, xp);

  for (int c = 0; c < 3; c++) {
    k_mom     <<<GN, 256, 0, stream>>>(xp, nsd, mom);
    k_P       <<<GN, 256, 0, stream>>>(xp, mom, cmom, w1a, b1a, g1a, be1a, wexy, stats, P);
    k_fusedagg<<<GW, 256, 0, stream>>>(starts, edg, P, wexy, w2tf, b1bf, tzb, gmsB, gzqB);
    k_hpre2   <<<GN, 256, 0, stream>>>(xp, tzb, starts, gmsB, gzqB, w1b, b1b, g1b, be1b,
                                       w2aT, hpre, SUM3, SSQ3);
    k_comb    <<<GN, 256, 0, stream>>>(hpre, SUM3, SSQ3, g2a, be2a, w2b, b2b, xp,
                                       mom, gmsB, gzqB);
  }

  k_p5<<<GN, 256, 0, stream>>>(xp, wpaT, hpre, SUM4, SSQ4);
  k_p6<<<GN, 256, 0, stream>>>(hpre, SUM4, SSQ4, gpa, bepa, wpb, bpb, yq, SUM5, SSQ5);
  k_p7<<<GN, 256, 0, stream>>>(yq, SUM5, SSQ5, gpb, bepb, (float*)d_out);
}

// Round 16
// 3830.896 us; speedup vs baseline: 1.0767x; 1.0767x over previous
//
#include <hip/hip_runtime.h>
#include <hip/hip_bf16.h>
#include <cstddef>

#define NN 100000
#define EE 3200000
#define NBIN 64
static const float EF = 3200000.0f;
#define INVN (1.0f / 100000.0f)

typedef __attribute__((ext_vector_type(8))) short bf16x8;
typedef __attribute__((ext_vector_type(16))) float f32x16;

// ---------- helpers ----------

__device__ __forceinline__ float wsum(float v) {
  #pragma unroll
  for (int off = 32; off > 0; off >>= 1) v += __shfl_down(v, off, 64);
  return v;  // lane 0 holds wave total
}

// block-level reduce of 32 sums + 32 sumsq -> global atomics. red = shared float[256].
__device__ __forceinline__ void reduce64(float sum[32], float ssq[32], float* red,
                                         float* __restrict__ gsum, float* __restrict__ gssq) {
  const int wid = threadIdx.x >> 6, lane = threadIdx.x & 63;
  #pragma unroll
  for (int j = 0; j < 32; j++) {
    float a = wsum(sum[j]);
    float b = wsum(ssq[j]);
    if (lane == 0) { red[wid * 64 + j] = a; red[wid * 64 + 32 + j] = b; }
  }
  __syncthreads();
  if (threadIdx.x < 64) {
    float t = red[threadIdx.x] + red[64 + threadIdx.x] + red[128 + threadIdx.x] + red[192 + threadIdx.x];
    if (threadIdx.x < 32) unsafeAtomicAdd(&gsum[threadIdx.x], t);
    else                  unsafeAtomicAdd(&gssq[threadIdx.x - 32], t);
  }
}

__device__ __forceinline__ void loadrow(const float* __restrict__ xp, int s, float in[13]) {
  const float4* xr = reinterpret_cast<const float4*>(xp + (size_t)s * 12);
  float4 r0 = xr[0], r1 = xr[1], r2 = xr[2];
  in[0]=r0.x; in[1]=r0.y; in[2]=r0.z; in[3]=r0.w; in[4]=r1.x; in[5]=r1.y; in[6]=r1.z; in[7]=r1.w;
  in[8]=r2.x; in[9]=r2.y; in[10]=r2.z;
}

// pack one edge's src-side contribution: [deg:1 @bit54 | (ey+8)*2^14 @bit27 | (ex+8)*2^14 @bit0]
__device__ __forceinline__ unsigned long long packsea(float x, float y) {
  unsigned int xq = (unsigned int)(fmaf(x, 16384.f, 131072.f) + 0.5f);
  unsigned int yq = (unsigned int)(fmaf(y, 16384.f, 131072.f) + 0.5f);
  return (1ULL << 54) | ((unsigned long long)yq << 27) | (unsigned long long)xq;
}

__device__ __forceinline__ short tobf(float f) {
  return (short)((__float_as_uint(f) + 0x8000u) >> 16);   // round-to-nearest
}
__device__ __forceinline__ float bfhi(float f) {          // exact bf16-truncation (RTZ)
  return __uint_as_float(__float_as_uint(f) & 0xFFFF0000u);
}
__device__ __forceinline__ short bfhi_s(float f) {
  return (short)(__float_as_uint(f) >> 16);
}

// ---------- setup kernels ----------

// w2tf[j][k] = d_j * w1b[k][j] (d_j = sign(g1b_j)); b1bf[j] = d_j*b1b[j];
// w2aT[j][0..42]+bias at 43; wpaT[j][0..10]+bias at 11
__global__ __launch_bounds__(256) void k_wprep(const float* __restrict__ w1b,
    const float* __restrict__ b1b, const float* __restrict__ g1b,
    const float* __restrict__ w2a, const float* __restrict__ b2a,
    const float* __restrict__ wpa, const float* __restrict__ bpa,
    float* __restrict__ w2tf, float* __restrict__ b1bf,
    float* __restrict__ w2aT, float* __restrict__ wpaT) {
  int t = threadIdx.x;
  for (int i = t; i < 1024; i += 256) {
    int j = i >> 5, k = i & 31;
    float d = (g1b[j] >= 0.f) ? 1.f : -1.f;
    w2tf[j * 32 + k] = d * w1b[k * 32 + j];
  }
  for (int i = t; i < 32 * 43; i += 256) { int j = i & 31, k = i >> 5; w2aT[j * 44 + k] = w2a[k * 32 + j]; }
  for (int i = t; i < 32 * 11; i += 256) { int j = i & 31, k = i >> 5; wpaT[j * 12 + k] = wpa[k * 32 + j]; }
  if (t < 32) {
    float d = (g1b[t] >= 0.f) ? 1.f : -1.f;
    b1bf[t] = d * b1b[t];
    w2aT[t * 44 + 43] = b2a[t];
    wpaT[t * 12 + 11] = bpa[t];
  }
}

// one edge pass: cnt atomic (returned value = rank within dst),
// ONE u64 fixed-point atomic for (deg, seaX, seaY) per edge, global ea moments in registers
__global__ __launch_bounds__(256) void k_prep(const int* __restrict__ dst, const int* __restrict__ src,
    const float* __restrict__ ea, int* __restrict__ cnt, int* __restrict__ rank,
    unsigned long long* __restrict__ nsd, float* __restrict__ cmom) {
  float p0 = 0, p1 = 0, p2 = 0, p3 = 0, p4 = 0;
  const int S = gridDim.x * 256;
  for (int g = blockIdx.x * 256 + threadIdx.x; g < EE / 4; g += S) {
    int4 d4 = reinterpret_cast<const int4*>(dst)[g];
    int4 s4 = reinterpret_cast<const int4*>(src)[g];
    float4 e0 = reinterpret_cast<const float4*>(ea)[2 * g];
    float4 e1 = reinterpret_cast<const float4*>(ea)[2 * g + 1];
    int r0 = atomicAdd(&cnt[d4.x], 1);
    int r1 = atomicAdd(&cnt[d4.y], 1);
    int r2 = atomicAdd(&cnt[d4.z], 1);
    int r3 = atomicAdd(&cnt[d4.w], 1);
    reinterpret_cast<int4*>(rank)[g] = make_int4(r0, r1, r2, r3);
    atomicAdd(&nsd[s4.x], packsea(e0.x, e0.y));
    atomicAdd(&nsd[s4.y], packsea(e0.z, e0.w));
    atomicAdd(&nsd[s4.z], packsea(e1.x, e1.y));
    atomicAdd(&nsd[s4.w], packsea(e1.z, e1.w));
    p0 += e0.x * e0.x + e0.z * e0.z + e1.x * e1.x + e1.z * e1.z;
    p1 += e0.x * e0.y + e0.z * e0.w + e1.x * e1.y + e1.z * e1.w;
    p2 += e0.y * e0.y + e0.w * e0.w + e1.y * e1.y + e1.w * e1.w;
    p3 += e0.x + e0.z + e1.x + e1.z;
    p4 += e0.y + e0.w + e1.y + e1.w;
  }
  p0 = wsum(p0); p1 = wsum(p1); p2 = wsum(p2); p3 = wsum(p3); p4 = wsum(p4);
  if ((threadIdx.x & 63) == 0) {
    unsafeAtomicAdd(&cmom[0], p0); unsafeAtomicAdd(&cmom[1], p1); unsafeAtomicAdd(&cmom[2], p2);
    unsafeAtomicAdd(&cmom[3], p3); unsafeAtomicAdd(&cmom[4], p4);
  }
}

__global__ __launch_bounds__(1024) void k_scan(const int* __restrict__ cnt,
                                               int* __restrict__ starts) {
  __shared__ int part[1024];
  const int T = 1024, CH = (NN + T - 1) / T;
  int t = threadIdx.x;
  int lo = t * CH, hi = min(lo + CH, NN);
  int s = 0;
  for (int i = lo; i < hi; i++) s += cnt[i];
  part[t] = s; __syncthreads();
  for (int off = 1; off < T; off <<= 1) {
    int v = (t >= off) ? part[t - off] : 0;
    __syncthreads();
    part[t] += v;
    __syncthreads();
  }
  int run = part[t] - s;  // exclusive prefix
  for (int i = lo; i < hi; i++) { starts[i] = run; run += cnt[i]; }
  if (t == T - 1) starts[NN] = EE;
}

// scatter packed 16B edge records (src, ea.x, ea.y, 0) into CSR order; NO atomics
__global__ __launch_bounds__(256) void k_scatter(const int* __restrict__ dst, const int* __restrict__ src,
    const float* __restrict__ ea, const int* __restrict__ starts, const int* __restrict__ rank,
    int4* __restrict__ edg) {
  const int S = gridDim.x * 256;
  for (int g = blockIdx.x * 256 + threadIdx.x; g < EE / 4; g += S) {
    int4 d4 = reinterpret_cast<const int4*>(dst)[g];
    int4 s4 = reinterpret_cast<const int4*>(src)[g];
    int4 r4 = reinterpret_cast<const int4*>(rank)[g];
    float4 e0 = reinterpret_cast<const float4*>(ea)[2 * g];
    float4 e1 = reinterpret_cast<const float4*>(ea)[2 * g + 1];
    edg[starts[d4.x] + r4.x] = make_int4(s4.x, __float_as_int(e0.x), __float_as_int(e0.y), 0);
    edg[starts[d4.y] + r4.y] = make_int4(s4.y, __float_as_int(e0.z), __float_as_int(e0.w), 0);
    edg[starts[d4.z] + r4.z] = make_int4(s4.z, __float_as_int(e1.x), __float_as_int(e1.y), 0);
    edg[starts[d4.w] + r4.w] = make_int4(s4.w, __float_as_int(e1.z), __float_as_int(e1.w), 0);
  }
}

// padded node rows: xp[n][0..9]=x cols 0..9, [10]=x col10 (current), [11]=0
__global__ __launch_bounds__(256) void k_xp(const float* __restrict__ x, float* __restrict__ xp) {
  int n = blockIdx.x * 256 + threadIdx.x;
  if (n >= NN) return;
  float v[11];
  #pragma unroll
  for (int k = 0; k < 11; k++) v[k] = x[(size_t)n * 11 + k];
  float4* o = reinterpret_cast<float4*>(xp + (size_t)n * 12);
  o[0] = make_float4(v[0], v[1], v[2], v[3]);
  o[1] = make_float4(v[4], v[5], v[6], v[7]);
  o[2] = make_float4(v[8], v[9], v[10], 0.f);
}

// ---------- per-conv: input moments (node pass) ----------
__global__ __launch_bounds__(256) void k_mom(const float* __restrict__ xp,
                                             const unsigned long long* __restrict__ nsd,
                                             float* __restrict__ mom) {
  const int n = blockIdx.x * 256 + threadIdx.x;
  const int lane = threadIdx.x & 63;
  float v[11]; float w = 0.f; float sx = 0.f, sy = 0.f;
  #pragma unroll
  for (int k = 0; k < 11; k++) v[k] = 0.f;
  if (n < NN) {
    unsigned long long pv = nsd[n];
    float dg = (float)(unsigned int)(pv >> 54);
    float sxf = (float)(unsigned int)(pv & 0x7FFFFFFull);
    float syf = (float)(unsigned int)((pv >> 27) & 0x7FFFFFFull);
    w = dg;
    sx = sxf * (1.f / 16384.f) - 8.f * dg;
    sy = syf * (1.f / 16384.f) - 8.f * dg;
    loadrow(xp, n, v);
  }
  int ch = 0;
  #pragma unroll
  for (int a = 0; a < 11; a++) {
    float r = wsum(w * v[a]);
    if (lane == 0) unsafeAtomicAdd(&mom[ch], r);
    ch++;
  }
  #pragma unroll
  for (int a = 0; a < 11; a++) {
    #pragma unroll
    for (int b = a; b < 11; b++) {
      float r = wsum(w * v[a] * v[b]);
      if (lane == 0) unsafeAtomicAdd(&mom[ch], r);
      ch++;
    }
  }
  #pragma unroll
  for (int a = 0; a < 11; a++) {
    float rx = wsum(v[a] * sx);
    if (lane == 0) unsafeAtomicAdd(&mom[ch], rx);
    ch++;
    float ry = wsum(v[a] * sy);
    if (lane == 0) unsafeAtomicAdd(&mom[ch], ry);
    ch++;
  }
}

__device__ __forceinline__ float msym(const float* mom, const float* cmom, int k, int l) {
  int a = min(k, l), b = max(k, l);
  if (b < 11) return mom[11 + a * 11 - a * (a - 1) / 2 + (b - a)];
  if (a < 11) return mom[77 + a * 2 + (b - 11)];
  return cmom[(a - 11) + (b - 11)];
}

// ---------- k_P: fused fin1 (per-block BN fold) + P precompute ----------
__global__ __launch_bounds__(256) void k_P(const float* __restrict__ xp,
    const float* __restrict__ mom, const float* __restrict__ cmom,
    const float* __restrict__ w1a, const float* __restrict__ b1a,
    const float* __restrict__ g1a, const float* __restrict__ be1a,
    float* __restrict__ wexy, float* __restrict__ statsbase, float* __restrict__ P) {
  __shared__ float w1fs[32 * 14];
  const int t = threadIdx.x;
  if (t < 32) {
    const int jj = t;
    float w[13], S[13];
    #pragma unroll
    for (int k = 0; k < 13; k++) w[k] = w1a[k * 32 + jj];
    #pragma unroll
    for (int k = 0; k < 11; k++) S[k] = mom[k];
    S[11] = cmom[3]; S[12] = cmom[4];
    float lin = 0.f;
    #pragma unroll
    for (int k = 0; k < 13; k++) lin = fmaf(w[k], S[k], lin);
    float quad = 0.f;
    #pragma unroll
    for (int k = 0; k < 13; k++)
      #pragma unroll
      for (int l = 0; l < 13; l++) quad = fmaf(w[k] * w[l], msym(mom, cmom, k, l), quad);
    const float invE = 1.f / EF;
    float b = b1a[jj];
    float mean = fmaf(lin, invE, b);
    float ey2 = (quad + 2.f * b * lin) * invE + b * b;
    float var = fmaxf(ey2 - mean * mean, 0.f);
    float A = g1a[jj] * rsqrtf(var + 1e-5f);
    float C = be1a[jj] - mean * A;
    #pragma unroll
    for (int k = 0; k < 11; k++) w1fs[jj * 14 + k] = A * w[k];
    w1fs[jj * 14 + 11] = 0.f; w1fs[jj * 14 + 12] = 0.f;
    w1fs[jj * 14 + 13] = fmaf(A, b, C);
    if (blockIdx.x == 0) { wexy[jj] = A * w[11]; wexy[32 + jj] = A * w[12]; }
  }
  if (blockIdx.x == 0 && t >= 64 && t < 128) statsbase[t] = 0.f;  // SUM3/SSQ3
  __syncthreads();
  const int n = blockIdx.x * 256 + t;
  if (n >= NN) return;
  float xv[11];
  loadrow(xp, n, xv);
  float4* op = reinterpret_cast<float4*>(P + (size_t)n * 32);
  #pragma unroll
  for (int jj = 0; jj < 8; jj++) {
    float o[4];
    #pragma unroll
    for (int u = 0; u < 4; u++) {
      int j = 4 * jj + u;
      const float* wr = w1fs + j * 14;
      float acc = wr[13];
      #pragma unroll
      for (int k = 0; k < 11; k++) acc = fmaf(xv[k], wr[k], acc);
      o[u] = acc;
    }
    op[jj] = make_float4(o[0], o[1], o[2], o[3]);
  }
}

// ---------- fused edge pass (MFMA engine, hi/lo split + masked rows) ----------
// One WAVE per node (grid-stride). A = m (bf16 hi+lo), B = folded W (bf16 hi+lo, reg-resident).
// z = A_hi*B_hi + A_hi*B_lo + A_lo*B_hi (3-product; dropped A_lo*B_lo ~1e-5 rel).
// Pad lanes (vm=0) give zero A rows. tz/zq use per-row validity via the VERIFIED D row map
// row = (rg&3)+8*(rg>>2)+4*(lane>>5) (guide m74/m101; R11 cross-validated vs fp32 engine).
__global__ __launch_bounds__(256, 4) void k_fusedagg(
    const int* __restrict__ starts, const int4* __restrict__ edg,
    const float* __restrict__ P, const float* __restrict__ wexy,
    const float* __restrict__ w2tf, const float* __restrict__ b1bf,
    float* __restrict__ tzb, float* __restrict__ gms, float* __restrict__ gzq) {
  const int tid = threadIdx.x;
  const int wid = tid >> 6, lane = tid & 63;
  const int j = lane & 31;      // channel (D col), edge slot for A
  const int h = lane >> 5;      // k-slice half / D row-quadrant bit
  const int k1 = 8 * h;
  const int k2 = 16 + 8 * h;
  float wexk[16], weyk[16];
  #pragma unroll
  for (int i = 0; i < 8; i++) {
    wexk[i]     = wexy[k1 + i];  weyk[i]     = wexy[32 + k1 + i];
    wexk[8 + i] = wexy[k2 + i];  weyk[8 + i] = wexy[32 + k2 + i];
  }
  bf16x8 B1h, B1l, B2h, B2l;
  #pragma unroll
  for (int i = 0; i < 8; i++) {
    float w1 = w2tf[j * 32 + k1 + i];
    B1h[i] = bfhi_s(w1); B1l[i] = tobf(w1 - bfhi(w1));
    float w2 = w2tf[j * 32 + k2 + i];
    B2h[i] = bfhi_s(w2); B2l[i] = tobf(w2 - bfhi(w2));
  }
  const float bz = b1bf[j];
  float ms[16];
  #pragma unroll
  for (int i = 0; i < 16; i++) ms[i] = 0.f;
  float zq = 0.f;
  const int nwaves = gridDim.x * 4;
  for (int n = blockIdx.x * 4 + wid; n < NN; n += nwaves) {
    const int lo = starts[n], hi = starts[n + 1];
    float tzn = -3.0e38f;
    for (int base = lo; base < hi; base += 32) {
      const int v = min(hi - base, 32);
      const bool ev = j < v;
      const int4 r = edg[ev ? (base + j) : (hi - 1)];
      const float ex = __int_as_float(r.y), ey = __int_as_float(r.z);
      const float* pr = P + (size_t)r.x * 32;
      const float4 p0 = *reinterpret_cast<const float4*>(pr + k1);
      const float4 p1 = *reinterpret_cast<const float4*>(pr + k1 + 4);
      const float4 p2 = *reinterpret_cast<const float4*>(pr + k2);
      const float4 p3 = *reinterpret_cast<const float4*>(pr + k2 + 4);
      const float vm = ev ? 1.f : 0.f;
      float mv[16];
      mv[0]  = vm * fmaxf(0.f, fmaf(ex, wexk[0],  fmaf(ey, weyk[0],  p0.x)));
      mv[1]  = vm * fmaxf(0.f, fmaf(ex, wexk[1],  fmaf(ey, weyk[1],  p0.y)));
      mv[2]  = vm * fmaxf(0.f, fmaf(ex, wexk[2],  fmaf(ey, weyk[2],  p0.z)));
      mv[3]  = vm * fmaxf(0.f, fmaf(ex, wexk[3],  fmaf(ey, weyk[3],  p0.w)));
      mv[4]  = vm * fmaxf(0.f, fmaf(ex, wexk[4],  fmaf(ey, weyk[4],  p1.x)));
      mv[5]  = vm * fmaxf(0.f, fmaf(ex, wexk[5],  fmaf(ey, weyk[5],  p1.y)));
      mv[6]  = vm * fmaxf(0.f, fmaf(ex, wexk[6],  fmaf(ey, weyk[6],  p1.z)));
      mv[7]  = vm * fmaxf(0.f, fmaf(ex, wexk[7],  fmaf(ey, weyk[7],  p1.w)));
      mv[8]  = vm * fmaxf(0.f, fmaf(ex, wexk[8],  fmaf(ey, weyk[8],  p2.x)));
      mv[9]  = vm * fmaxf(0.f, fmaf(ex, wexk[9],  fmaf(ey, weyk[9],  p2.y)));
      mv[10] = vm * fmaxf(0.f, fmaf(ex, wexk[10], fmaf(ey, weyk[10], p2.z)));
      mv[11] = vm * fmaxf(0.f, fmaf(ex, wexk[11], fmaf(ey, weyk[11], p2.w)));
      mv[12] = vm * fmaxf(0.f, fmaf(ex, wexk[12], fmaf(ey, weyk[12], p3.x)));
      mv[13] = vm * fmaxf(0.f, fmaf(ex, wexk[13], fmaf(ey, weyk[13], p3.y)));
      mv[14] = vm * fmaxf(0.f, fmaf(ex, wexk[14], fmaf(ey, weyk[14], p3.z)));
      mv[15] = vm * fmaxf(0.f, fmaf(ex, wexk[15], fmaf(ey, weyk[15], p3.w)));
      #pragma unroll
      for (int i = 0; i < 16; i++) ms[i] += mv[i];
      bf16x8 A1h, A1l, A2h, A2l;
      #pragma unroll
      for (int i = 0; i < 8; i++) {
        A1h[i] = bfhi_s(mv[i]);     A1l[i] = tobf(mv[i] - bfhi(mv[i]));
        A2h[i] = bfhi_s(mv[8 + i]); A2l[i] = tobf(mv[8 + i] - bfhi(mv[8 + i]));
      }
      f32x16 acc;
      #pragma unroll
      for (int i = 0; i < 16; i++) acc[i] = 0.f;
      acc = __builtin_amdgcn_mfma_f32_32x32x16_bf16(A1h, B1h, acc, 0, 0, 0);
      acc = __builtin_amdgcn_mfma_f32_32x32x16_bf16(A1h, B1l, acc, 0, 0, 0);
      acc = __builtin_amdgcn_mfma_f32_32x32x16_bf16(A1l, B1h, acc, 0, 0, 0);
      acc = __builtin_amdgcn_mfma_f32_32x32x16_bf16(A2h, B2h, acc, 0, 0, 0);
      acc = __builtin_amdgcn_mfma_f32_32x32x16_bf16(A2h, B2l, acc, 0, 0, 0);
      acc = __builtin_amdgcn_mfma_f32_32x32x16_bf16(A2l, B2h, acc, 0, 0, 0);
      const int rb = base + 4 * h;
      #pragma unroll
      for (int rg = 0; rg < 16; rg++) {
        const int row = (rg & 3) + 8 * (rg >> 2);
        const bool rv = (rb + row) < hi;
        const float z = acc[rg] + bz;
        tzn = fmaxf(tzn, rv ? z : -3.0e38f);
        const float zz = rv ? z : 0.f;
        zq = fmaf(zz, zz, zq);
      }
    }
    tzn = fmaxf(tzn, __shfl_xor(tzn, 32, 64));
    if (lane < 32) tzb[(size_t)n * 32 + j] = tzn;
  }
  // ---- kernel-end stat flush ----
  const int bin = blockIdx.x & (NBIN - 1);
  float zqT = zq + __shfl_xor(zq, 32, 64);
  if (lane < 32) unsafeAtomicAdd(&gzq[bin * 32 + j], zqT);
  #pragma unroll
  for (int i = 0; i < 16; i++) {
    ms[i] += __shfl_xor(ms[i], 16, 64);
    ms[i] += __shfl_xor(ms[i], 8, 64);
    ms[i] += __shfl_xor(ms[i], 4, 64);
    ms[i] += __shfl_xor(ms[i], 2, 64);
    ms[i] += __shfl_xor(ms[i], 1, 64);
  }
  if (lane == 0) {
    #pragma unroll
    for (int i = 0; i < 8; i++) unsafeAtomicAdd(&gms[bin * 32 + i], ms[i]);
    #pragma unroll
    for (int i = 0; i < 8; i++) unsafeAtomicAdd(&gms[bin * 32 + 16 + i], ms[8 + i]);
  }
  if (lane == 32) {
    #pragma unroll
    for (int i = 0; i < 8; i++) unsafeAtomicAdd(&gms[bin * 32 + 8 + i], ms[i]);
    #pragma unroll
    for (int i = 0; i < 8; i++) unsafeAtomicAdd(&gms[bin * 32 + 24 + i], ms[8 + i]);
  }
}

// ---------- hpre2: fused fin2 (bins -> A2d/C2 per block) + h compute + stats ----------
__global__ __launch_bounds__(256) void k_hpre2(const float* __restrict__ xp,
    const float* __restrict__ tzb, const int* __restrict__ starts,
    const float* __restrict__ gms, const float* __restrict__ gzq,
    const float* __restrict__ w1b, const float* __restrict__ b1b,
    const float* __restrict__ g1b, const float* __restrict__ be1b,
    const float* __restrict__ w2aT,
    float* __restrict__ hpre, float* __restrict__ gsum, float* __restrict__ gssq) {
  __shared__ float red[256], a2s[32], c2s[32], smm[32], szq[32];
  const int t = threadIdx.x;
  if (t < 32) {
    float msj = 0.f, zqj = 0.f;
    for (int b = 0; b < NBIN; b++) { msj += gms[b * 32 + t]; zqj += gzq[b * 32 + t]; }
    smm[t] = msj; szq[t] = zqj;
  }
  __syncthreads();
  if (t < 32) {
    float zs = EF * b1b[t];
    #pragma unroll
    for (int k = 0; k < 32; k++) zs = fmaf(w1b[k * 32 + t], smm[k], zs);
    const float invE = 1.f / EF;
    float mu = zs * invE;
    float var = fmaxf(szq[t] * invE - mu * mu, 0.f);
    float A = g1b[t] * rsqrtf(var + 1e-5f);
    float C = be1b[t] - mu * A;
    float d = (g1b[t] >= 0.f) ? 1.f : -1.f;
    a2s[t] = A * d; c2s[t] = C;
  }
  __syncthreads();
  const int n = blockIdx.x * 256 + t;
  float hh[32], hv[32];
  #pragma unroll
  for (int j = 0; j < 32; j++) hv[j] = 0.f;
  if (n < NN) {
    float xv[11];
    loadrow(xp, n, xv);
    const int dg = starts[n + 1] - starts[n];
    float av[32];
    if (dg > 0) {
      const float4* tp = reinterpret_cast<const float4*>(tzb + (size_t)n * 32);
      #pragma unroll
      for (int j = 0; j < 8; j++) {
        float4 v = tp[j];
        av[4 * j]     = fmaxf(0.f, fmaf(a2s[4 * j],     v.x, c2s[4 * j]));
        av[4 * j + 1] = fmaxf(0.f, fmaf(a2s[4 * j + 1], v.y, c2s[4 * j + 1]));
        av[4 * j + 2] = fmaxf(0.f, fmaf(a2s[4 * j + 2], v.z, c2s[4 * j + 2]));
        av[4 * j + 3] = fmaxf(0.f, fmaf(a2s[4 * j + 3], v.w, c2s[4 * j + 3]));
      }
    } else {
      #pragma unroll
      for (int j = 0; j < 32; j++) av[j] = 0.f;
    }
    #pragma unroll
    for (int j = 0; j < 32; j++) {
      const float* wr = w2aT + j * 44;
      float acc = wr[43];
      #pragma unroll
      for (int k = 0; k < 11; k++) acc = fmaf(xv[k], wr[k], acc);
      #pragma unroll
      for (int k = 0; k < 32; k++) acc = fmaf(av[k], wr[11 + k], acc);
      hv[j] = acc;
    }
    float4* hp = reinterpret_cast<float4*>(hpre + (size_t)n * 32);
    #pragma unroll
    for (int j = 0; j < 8; j++)
      hp[j] = make_float4(hv[4 * j], hv[4 * j + 1], hv[4 * j + 2], hv[4 * j + 3]);
  }
  #pragma unroll
  for (int j = 0; j < 32; j++) hh[j] = hv[j] * hv[j];
  reduce64(hv, hh, red, gsum, gssq);
}

// ---------- comb: fused fin3 + new col10; block0 zeroes mom & gms/gzq for next conv ----------
__global__ __launch_bounds__(256) void k_comb(const float* __restrict__ hpre,
    const float* __restrict__ SUM3, const float* __restrict__ SSQ3,
    const float* __restrict__ g2a, const float* __restrict__ be2a,
    const float* __restrict__ w2b, const float* __restrict__ b2b, float* __restrict__ xp,
    float* __restrict__ mom, float* __restrict__ gms, float* __restrict__ gzq) {
  __shared__ float a3s[32], c3s[32];
  const int t = threadIdx.x;
  if (t < 32) {
    float mu = SUM3[t] * INVN;
    float var = fmaxf(SSQ3[t] * INVN - mu * mu, 0.f);
    float s = rsqrtf(var + 1e-5f) * g2a[t];
    a3s[t] = s; c3s[t] = be2a[t] - mu * s;
  }
  __syncthreads();
  const int n = blockIdx.x * 256 + t;
  if (n < NN) {
    const float4* hp = reinterpret_cast<const float4*>(hpre + (size_t)n * 32);
    float acc = b2b[0];
    #pragma unroll
    for (int j = 0; j < 8; j++) {
      float4 v = hp[j];
      acc += fmaxf(0.f, fmaf(v.x, a3s[4 * j],     c3s[4 * j]))     * w2b[4 * j];
      acc += fmaxf(0.f, fmaf(v.y, a3s[4 * j + 1], c3s[4 * j + 1])) * w2b[4 * j + 1];
      acc += fmaxf(0.f, fmaf(v.z, a3s[4 * j + 2], c3s[4 * j + 2])) * w2b[4 * j + 2];
      acc += fmaxf(0.f, fmaf(v.w, a3s[4 * j + 3], c3s[4 * j + 3])) * w2b[4 * j + 3];
    }
    xp[(size_t)n * 12 + 10] = fmaxf(acc, 0.f);
  }
  if (blockIdx.x == 0) {
    if (t < 128) mom[t] = 0.f;
    for (int i = t; i < NBIN * 32; i += 256) { gms[i] = 0.f; gzq[i] = 0.f; }
  }
}

// ---------- power MLP ----------

__global__ __launch_bounds__(256) void k_p5(const float* __restrict__ xp, const float* __restrict__ wpaT,
                                            float* __restrict__ ybuf,
                                            float* __restrict__ gsum, float* __restrict__ gssq) {
  __shared__ float red[256];
  const int n = blockIdx.x * 256 + threadIdx.x;
  float y[32], yy[32];
  #pragma unroll
  for (int j = 0; j < 32; j++) y[j] = 0.f;
  if (n < NN) {
    float xv[11];
    loadrow(xp, n, xv);
    #pragma unroll
    for (int j = 0; j < 32; j++) {
      const float* wr = wpaT + j * 12;
      float acc = wr[11];
      #pragma unroll
      for (int k = 0; k < 11; k++) acc = fmaf(xv[k], wr[k], acc);
      y[j] = acc;
    }
    float4* yp = reinterpret_cast<float4*>(ybuf + (size_t)n * 32);
    #pragma unroll
    for (int j = 0; j < 8; j++)
      yp[j] = make_float4(y[4 * j], y[4 * j + 1], y[4 * j + 2], y[4 * j + 3]);
  }
  #pragma unroll
  for (int j = 0; j < 32; j++) yy[j] = y[j] * y[j];
  reduce64(y, yy, red, gsum, gssq);
}

// p6: fused fin4 (SUM4 -> a4/c4 per block) + yq + scalar stats
__global__ __launch_bounds__(256) void k_p6(const float* __restrict__ ybuf,
    const float* __restrict__ SUM4, const float* __restrict__ SSQ4,
    const float* __restrict__ gpa, const float* __restrict__ bepa,
    const float* __restrict__ wpb, const float* __restrict__ bpb,
    float* __restrict__ yq, float* __restrict__ gsum, float* __restrict__ gssq) {
  __shared__ float red[8], a4s[32], c4s[32];
  const int t = threadIdx.x;
  if (t < 32) {
    float mu = SUM4[t] * INVN;
    float var = fmaxf(SSQ4[t] * INVN - mu * mu, 0.f);
    float s = rsqrtf(var + 1e-5f) * gpa[t];
    a4s[t] = s; c4s[t] = bepa[t] - mu * s;
  }
  __syncthreads();
  const int n = blockIdx.x * 256 + t;
  float sum = 0.f, ssq = 0.f;
  if (n < NN) {
    const float4* yp = reinterpret_cast<const float4*>(ybuf + (size_t)n * 32);
    float q = bpb[0];
    #pragma unroll
    for (int j = 0; j < 8; j++) {
      float4 v = yp[j];
      q = fmaf(fmaxf(0.f, fmaf(v.x, a4s[4 * j],     c4s[4 * j])),     wpb[4 * j],     q);
      q = fmaf(fmaxf(0.f, fmaf(v.y, a4s[4 * j + 1], c4s[4 * j + 1])), wpb[4 * j + 1], q);
      q = fmaf(fmaxf(0.f, fmaf(v.z, a4s[4 * j + 2], c4s[4 * j + 2])), wpb[4 * j + 2], q);
      q = fmaf(fmaxf(0.f, fmaf(v.w, a4s[4 * j + 3], c4s[4 * j + 3])), wpb[4 * j + 3], q);
    }
    yq[n] = q;
    sum = q; ssq = q * q;
  }
  float s = wsum(sum), qq = wsum(ssq);
  const int wid = t >> 6, lane = t & 63;
  if (lane == 0) { red[wid] = s; red[4 + wid] = qq; }
  __syncthreads();
  if (t == 0) {
    unsafeAtomicAdd(&gsum[0], red[0] + red[1] + red[2] + red[3]);
    unsafeAtomicAdd(&gssq[0], red[4] + red[5] + red[6] + red[7]);
  }
}

// p7: fused fin5
__global__ __launch_bounds__(256) void k_p7(const float* __restrict__ yq,
    const float* __restrict__ SUM5, const float* __restrict__ SSQ5,
    const float* __restrict__ gpb, const float* __restrict__ bepb, float* __restrict__ out) {
  const int n = blockIdx.x * 256 + threadIdx.x;
  if (n >= NN) return;
  float mu = SUM5[0] * INVN;
  float var = fmaxf(SSQ5[0] * INVN - mu * mu, 0.f);
  float a5 = rsqrtf(var + 1e-5f) * gpb[0];
  float c5 = bepb[0] - mu * a5;
  out[n] = fmaxf(0.f, fmaf(yq[n], a5, c5));
}

// ---------- host launch ----------

extern "C" void kernel_launch(void* const* d_in, const int* in_sizes, int n_in,
                              void* d_out, int out_size, void* d_ws, size_t ws_size,
                              hipStream_t stream) {
  const float* x    = (const float*)d_in[0];
  const float* ea   = (const float*)d_in[1];
  const int*   ei   = (const int*)d_in[2];
  const int*   srcp = ei;
  const int*   dstp = ei + EE;
  const float* w1a = (const float*)d_in[3],  *b1a = (const float*)d_in[4];
  const float* g1a = (const float*)d_in[5],  *be1a = (const float*)d_in[6];
  const float* w1b = (const float*)d_in[7],  *b1b = (const float*)d_in[8];
  const float* g1b = (const float*)d_in[9],  *be1b = (const float*)d_in[10];
  const float* w2a = (const float*)d_in[11], *b2a = (const float*)d_in[12];
  const float* g2a = (const float*)d_in[13], *be2a = (const float*)d_in[14];
  const float* w2b = (const float*)d_in[15], *b2b = (const float*)d_in[16];
  const float* wpa = (const float*)d_in[17], *bpa = (const float*)d_in[18];
  const float* gpa = (const float*)d_in[19], *bepa = (const float*)d_in[20];
  const float* wpb = (const float*)d_in[21], *bpb = (const float*)d_in[22];
  const float* gpb = (const float*)d_in[23], *bepb = (const float*)d_in[24];

  size_t off = 0;
  char* base = (char*)d_ws;
  auto alloc = [&](size_t bytes) -> void* {
    void* p = base + off;
    off += (bytes + 255) & ~(size_t)255;
    return p;
  };
  float* stats = (float*)alloc(2048);
  float* mom   = (float*)alloc(512);
  float* cmom  = (float*)alloc(256);
  float* gmsB  = (float*)alloc(NBIN * 32 * 4);
  float* gzqB  = (float*)alloc(NBIN * 32 * 4);
  float* wexy  = (float*)alloc(64 * 4);
  float* w2tf  = (float*)alloc(32 * 32 * 4);
  float* b1bf  = (float*)alloc(256);
  float* w2aT  = (float*)alloc(32 * 44 * 4);
  float* wpaT  = (float*)alloc(32 * 12 * 4);
  int*   cnt    = (int*)alloc(NN * 4);
  unsigned long long* nsd = (unsigned long long*)alloc((size_t)NN * 8);
  int*   starts = (int*)alloc((NN + 1) * 4);
  int*   rank   = (int*)alloc((size_t)EE * 4);
  int4*  edg    = (int4*)alloc((size_t)EE * 16);
  float* xp     = (float*)alloc((size_t)NN * 12 * 4);
  float* P      = (float*)alloc((size_t)NN * 32 * 4);
  float* tzb    = (float*)alloc((size_t)NN * 32 * 4);
  float* hpre   = (float*)alloc((size_t)NN * 32 * 4);
  float* yq     = (float*)alloc(NN * 4);

  float *SUM3 = stats + 64,  *SSQ3 = stats + 96;
  float *SUM4 = stats + 128, *SSQ4 = stats + 160;
  float *SUM5 = stats + 192, *SSQ5 = stats + 224;

  hipMemsetAsync(stats, 0, 2048, stream);
  hipMemsetAsync(mom, 0, 512 + 256, stream);               // mom + cmom (contiguous)
  hipMemsetAsync(gmsB, 0, NBIN * 32 * 4 * 2, stream);      // gmsB + gzqB (contiguous)
  hipMemsetAsync(cnt, 0, NN * 4, stream);
  hipMemsetAsync(nsd, 0, (size_t)NN * 8, stream);

  const int GN = (NN + 255) / 256;          // 391
  const int GW = 2048;                      // fusedagg: 8192 waves, grid-stride over nodes
  const int GE4 = (EE / 4 + 255) / 256;     // 3125

  k_wprep  <<<1, 256, 0, stream>>>(w1b, b1b, g1b, w2a, b2a, wpa, bpa, w2tf, b1bf, w2aT, wpaT);
  k_prep   <<<GE4, 256, 0, stream>>>(dstp, srcp, ea, cnt, rank, nsd, cmom);
  k_scan   <<<1, 1024, 0, stream>>>(cnt, starts);
  k_scatter<<<GE4, 256, 0, stream>>>(dstp, srcp, ea, starts, rank, edg);
  k_xp     <<<GN, 256, 0, stream>>>(x, xp);

  for (int c = 0; c < 3; c++) {
    k_mom     <<<GN, 256, 0, stream>>>(xp, nsd, mom);
    k_P       <<<GN, 256, 0, stream>>>(xp, mom, cmom, w1a, b1a, g1a, be1a, wexy, stats, P);
    k_fusedagg<<<GW, 256, 0, stream>>>(starts, edg, P, wexy, w2tf, b1bf, tzb, gmsB, gzqB);
    k_hpre2   <<<GN, 256, 0, stream>>>(xp, tzb, starts, gmsB, gzqB, w1b, b1b, g1b, be1b,
                                       w2aT, hpre, SUM3, SSQ3);
    k_comb    <<<GN, 256, 0, stream>>>(hpre, SUM3, SSQ3, g2a, be2a, w2b, b2b, xp,
                                       mom, gmsB, gzqB);
  }

  k_p5<<<GN, 256, 0, stream>>>(xp, wpaT, hpre, SUM4, SSQ4);
  k_p6<<<GN, 256, 0, stream>>>(hpre, SUM4, SSQ4, gpa, bepa, wpb, bpb, yq, SUM5, SSQ5);
  k_p7<<<GN, 256, 0, stream>>>(yq, SUM5, SSQ5, gpb, bepb, (float*)d_out);
}